// Round 3
// baseline (87.535 us; speedup 1.0000x reference)
//
#include <hip/hip_runtime.h>

typedef short short8 __attribute__((ext_vector_type(8)));
typedef float f32x4 __attribute__((ext_vector_type(4)));

#define DK 64
#define TUSR 4   // user tiles (of 64 rows) per block

// f32 -> bf16 round-to-nearest-even
__device__ __forceinline__ short f2bf(float x) {
    unsigned u = __builtin_bit_cast(unsigned, x);
    unsigned r = (u + 0x7fffu + ((u >> 16) & 1u)) >> 16;
    return (short)r;
}

// ---------------- Phase 1: bf16 convert (value + square), natural layout ----
// ws (shorts): [wsU: NUP*64][wsU2: NUP*64][wsM: NMP*64][wsM2: NMP*64]
__global__ __launch_bounds__(256)
void fm_convert(const float* __restrict__ U, const float* __restrict__ M,
                short* __restrict__ ws, int NU, int NM, int NUP, int NMP) {
    int id = blockIdx.x * blockDim.x + threadIdx.x;
    int total = (NUP + NMP) * 8;
    if (id >= total) return;
    int rowg = id >> 3;
    int p = id & 7;                 // 8-short chunk within the 64-wide row
    const float* src; short *dv, *dq; int row, nvalid;
    if (rowg < NUP) {
        row = rowg; src = U; dv = ws; dq = ws + (size_t)NUP * DK; nvalid = NU;
    } else {
        row = rowg - NUP; src = M;
        dv = ws + (size_t)2 * NUP * DK; dq = dv + (size_t)NMP * DK; nvalid = NM;
    }
    short8 v8 = {0,0,0,0,0,0,0,0}, q8 = {0,0,0,0,0,0,0,0};
    if (row < nvalid) {
        const float* s = src + (size_t)row * DK + p * 8;
        float4 a = *(const float4*)(s);
        float4 b = *(const float4*)(s + 4);
        v8 = (short8){ f2bf(a.x), f2bf(a.y), f2bf(a.z), f2bf(a.w),
                       f2bf(b.x), f2bf(b.y), f2bf(b.z), f2bf(b.w) };
        q8 = (short8){ f2bf(a.x*a.x), f2bf(a.y*a.y), f2bf(a.z*a.z), f2bf(a.w*a.w),
                       f2bf(b.x*b.x), f2bf(b.y*b.y), f2bf(b.z*b.z), f2bf(b.w*b.w) };
    }
    *(short8*)(dv + (size_t)row * DK + p * 8) = v8;
    *(short8*)(dq + (size_t)row * DK + p * 8) = q8;
}

// ---------------- Phase 2: reg-resident fused double-GEMM, no LDS ----------
// Block: 128 movie cols (wave w owns 32) x TUSR*64 user rows (looped).
// B fragments live in VGPRs for the whole block; A fragments load straight
// from L2-resident ws. MFMA computed transposed (mfma(B,A)) so each lane
// holds 4 consecutive movie columns -> float4 nontemporal stores.
__global__ __launch_bounds__(256, 2)
void fm_gemm(const short* __restrict__ ws, float* __restrict__ out,
             int NM, int NMP, int NUP) {
    const int t = threadIdx.x;
    const int lane = t & 63;
    const int w = t >> 6;            // wave 0..3 -> movie quadrant
    const int lr = lane & 15;
    const int lk = lane >> 4;

    const int nb = blockIdx.y * 128 + w * 32;   // wave's movie base

    const short* gU  = ws;
    const short* gU2 = ws + (size_t)NUP * DK;
    const short* gM  = ws + (size_t)2 * NUP * DK;
    const short* gM2 = gM + (size_t)NMP * DK;

    // B fragments (movies): [n][ks], rows nb + n*16 + lr, K-chunk ks*4+lk
    short8 bv[2][2], bq[2][2];
#pragma unroll
    for (int n = 0; n < 2; ++n)
#pragma unroll
        for (int ks = 0; ks < 2; ++ks) {
            const size_t a = (size_t)(nb + n * 16 + lr) * DK + (ks * 4 + lk) * 8;
            bv[n][ks] = *(const short8*)(gM  + a);
            bq[n][ks] = *(const short8*)(gM2 + a);
        }

    const int ub0 = blockIdx.x * (64 * TUSR);
#pragma unroll
    for (int tt = 0; tt < TUSR; ++tt) {
        const int ub = ub0 + tt * 64;
        // A fragments (users): [m][ks]
        short8 av[4][2], aq[4][2];
#pragma unroll
        for (int m = 0; m < 4; ++m)
#pragma unroll
            for (int ks = 0; ks < 2; ++ks) {
                const size_t a = (size_t)(ub + m * 16 + lr) * DK + (ks * 4 + lk) * 8;
                av[m][ks] = *(const short8*)(gU  + a);
                aq[m][ks] = *(const short8*)(gU2 + a);
            }

        f32x4 s[4][2], q[4][2];
#pragma unroll
        for (int m = 0; m < 4; ++m)
#pragma unroll
            for (int n = 0; n < 2; ++n) {
                s[m][n] = (f32x4){0.f, 0.f, 0.f, 0.f};
                q[m][n] = (f32x4){0.f, 0.f, 0.f, 0.f};
            }

#pragma unroll
        for (int m = 0; m < 4; ++m)
#pragma unroll
            for (int n = 0; n < 2; ++n)
#pragma unroll
                for (int ks = 0; ks < 2; ++ks) {
                    // transposed: D[movie][user]
                    s[m][n] = __builtin_amdgcn_mfma_f32_16x16x32_bf16(bv[n][ks], av[m][ks], s[m][n], 0, 0, 0);
                    q[m][n] = __builtin_amdgcn_mfma_f32_16x16x32_bf16(bq[n][ks], aq[m][ks], q[m][n], 0, 0, 0);
                }

        // Epilogue: lane holds user row (ub+m*16+lr), movie cols nb+n*16+lk*4+{0..3}
#pragma unroll
        for (int m = 0; m < 4; ++m) {
            float* rowp = out + (size_t)(ub + m * 16 + lr) * NM;
#pragma unroll
            for (int n = 0; n < 2; ++n) {
                const int col = nb + n * 16 + lk * 4;
                if (col < NM) {
                    f32x4 sv = s[m][n], qv = q[m][n];
                    f32x4 r;
#pragma unroll
                    for (int i = 0; i < 4; ++i)
                        r[i] = 0.5f * (sv[i] * sv[i] - qv[i]);
                    __builtin_nontemporal_store(r, (f32x4*)(rowp + col));
                }
            }
        }
    }
}

// ---------------- Fallback (round-1 kernel) ---------------------------------
__global__ __launch_bounds__(256, 2)
void fm_fallback(const float* __restrict__ U, const float* __restrict__ M,
                 float* __restrict__ out, int NU, int NM) {
    __shared__ short sA [128 * DK];
    __shared__ short sA2[128 * DK];
    __shared__ short sB [128 * DK];
    __shared__ short sB2[128 * DK];

    const int t = threadIdx.x;
    const int lane = t & 63;
    const int w = t >> 6;
    const int wr = w >> 1;
    const int wc = w & 1;
    const int lr = lane & 15;
    const int lk = lane >> 4;

    const int mbase = blockIdx.x * 128;
    const int nbase = blockIdx.y * 128;

    const int r0 = t >> 4;
    const int c4 = t & 15;
    const int chunk = c4 >> 1;
    const int sub = c4 & 1;

    typedef short short4v __attribute__((ext_vector_type(4)));
#pragma unroll
    for (int i = 0; i < 8; ++i) {
        const int r = r0 + i * 16;
        const int sidx = r * DK + ((chunk ^ (r & 7)) << 3) + (sub << 2);
        {
            float4 v = make_float4(0.f, 0.f, 0.f, 0.f);
            const int gr = mbase + r;
            if (gr < NU) v = *(const float4*)(U + (size_t)gr * DK + c4 * 4);
            short4v b  = { f2bf(v.x), f2bf(v.y), f2bf(v.z), f2bf(v.w) };
            short4v b2 = { f2bf(v.x*v.x), f2bf(v.y*v.y), f2bf(v.z*v.z), f2bf(v.w*v.w) };
            *(short4v*)&sA[sidx] = b; *(short4v*)&sA2[sidx] = b2;
        }
        {
            float4 v = make_float4(0.f, 0.f, 0.f, 0.f);
            const int gr = nbase + r;
            if (gr < NM) v = *(const float4*)(M + (size_t)gr * DK + c4 * 4);
            short4v b  = { f2bf(v.x), f2bf(v.y), f2bf(v.z), f2bf(v.w) };
            short4v b2 = { f2bf(v.x*v.x), f2bf(v.y*v.y), f2bf(v.z*v.z), f2bf(v.w*v.w) };
            *(short4v*)&sB[sidx] = b; *(short4v*)&sB2[sidx] = b2;
        }
    }
    __syncthreads();

    f32x4 accS[4][4], accQ[4][4];
#pragma unroll
    for (int m = 0; m < 4; ++m)
#pragma unroll
        for (int n = 0; n < 4; ++n) {
            accS[m][n] = (f32x4){0.f,0.f,0.f,0.f};
            accQ[m][n] = (f32x4){0.f,0.f,0.f,0.f};
        }
#pragma unroll
    for (int ks = 0; ks < 2; ++ks) {
        short8 af[4], a2f[4], bfr[4], b2f[4];
        const int c = ks * 4 + lk;
#pragma unroll
        for (int m = 0; m < 4; ++m) {
            const int row = wr * 64 + m * 16 + lr;
            const int idx = row * DK + ((c ^ (row & 7)) << 3);
            af[m] = *(const short8*)&sA[idx]; a2f[m] = *(const short8*)&sA2[idx];
        }
#pragma unroll
        for (int n = 0; n < 4; ++n) {
            const int row = wc * 64 + n * 16 + lr;
            const int idx = row * DK + ((c ^ (row & 7)) << 3);
            bfr[n] = *(const short8*)&sB[idx]; b2f[n] = *(const short8*)&sB2[idx];
        }
#pragma unroll
        for (int m = 0; m < 4; ++m)
#pragma unroll
            for (int n = 0; n < 4; ++n) {
                accS[m][n] = __builtin_amdgcn_mfma_f32_16x16x32_bf16(af[m],  bfr[n], accS[m][n], 0, 0, 0);
                accQ[m][n] = __builtin_amdgcn_mfma_f32_16x16x32_bf16(a2f[m], b2f[n], accQ[m][n], 0, 0, 0);
            }
    }
#pragma unroll
    for (int m = 0; m < 4; ++m) {
        const int grow0 = mbase + wr * 64 + m * 16 + lk * 4;
#pragma unroll
        for (int n = 0; n < 4; ++n) {
            const int gcol = nbase + wc * 64 + n * 16 + lr;
            if (gcol < NM) {
                f32x4 s = accS[m][n]; f32x4 q = accQ[m][n];
#pragma unroll
                for (int r = 0; r < 4; ++r) {
                    const int grow = grow0 + r;
                    if (grow < NU)
                        out[(size_t)grow * NM + gcol] = 0.5f * (s[r]*s[r] - q[r]);
                }
            }
        }
    }
}

extern "C" void kernel_launch(void* const* d_in, const int* in_sizes, int n_in,
                              void* d_out, int out_size, void* d_ws, size_t ws_size,
                              hipStream_t stream) {
    const float* U = (const float*)d_in[0];
    const float* M = (const float*)d_in[1];
    float* out = (float*)d_out;
    const int NU = in_sizes[0] / DK;   // 1024
    const int NM = in_sizes[1] / DK;   // 50000
    const int NUP = NU;                // fast path requires NU % 256 == 0
    const int NMP = ((NM + 127) / 128) * 128;
    const size_t need = (size_t)(NUP + NMP) * DK * 2 * sizeof(short);

    if ((NU % (64 * TUSR) == 0) && (NM % 4 == 0) && ws_size >= need) {
        short* ws = (short*)d_ws;
        const int tasks = (NUP + NMP) * 8;
        fm_convert<<<(tasks + 255) / 256, 256, 0, stream>>>(U, M, ws, NU, NM, NUP, NMP);
        dim3 grid(NU / (64 * TUSR), NMP / 128);
        fm_gemm<<<grid, dim3(256), 0, stream>>>(ws, out, NM, NMP, NUP);
    } else {
        dim3 grid((NU + 127) / 128, (NM + 127) / 128);
        fm_fallback<<<grid, dim3(256), 0, stream>>>(U, M, out, NU, NM);
    }
}

// Round 4
// 82.116 us; speedup vs baseline: 1.0660x; 1.0660x over previous
//
#include <hip/hip_runtime.h>

typedef short short8 __attribute__((ext_vector_type(8)));
typedef float f32x4 __attribute__((ext_vector_type(4)));

#define DK 64
#define BM 64
#define BN 128
#define TUSR 4   // user tiles of 64 rows looped per block

// f32 -> bf16 round-to-nearest-even
__device__ __forceinline__ short f2bf(float x) {
    unsigned u = __builtin_bit_cast(unsigned, x);
    unsigned r = (u + 0x7fffu + ((u >> 16) & 1u)) >> 16;
    return (short)r;
}

__device__ __forceinline__ void gl_lds16(const void* g, void* l) {
    __builtin_amdgcn_global_load_lds(
        (const __attribute__((address_space(1))) unsigned int*)g,
        (__attribute__((address_space(3))) unsigned int*)l, 16, 0, 0);
}

// ---------------- Phase 1: bf16 convert (value + square) --------------------
// ws (shorts): [wsU: NUP*64][wsU2: NUP*64][wsM: NMP*64][wsM2: NMP*64]
// U rows are stored PRE-SWIZZLED (chunk p holds source chunk p^(row&7)) so a
// linear global_load_lds copy yields the XOR-swizzled LDS layout (rule #21:
// swizzle source + read, keep LDS dest linear). M rows are natural (read
// straight to registers, no LDS).
__global__ __launch_bounds__(256)
void fm_convert(const float* __restrict__ U, const float* __restrict__ M,
                short* __restrict__ ws, int NU, int NM, int NUP, int NMP) {
    int id = blockIdx.x * blockDim.x + threadIdx.x;
    int total = (NUP + NMP) * 8;
    if (id >= total) return;
    int rowg = id >> 3;
    int p = id & 7;                 // 8-short (16B) chunk within 64-wide row
    const float* src; short *dv, *dq; int row, nvalid, swz;
    if (rowg < NUP) {
        row = rowg; src = U; dv = ws; dq = ws + (size_t)NUP * DK;
        nvalid = NU; swz = 1;
    } else {
        row = rowg - NUP; src = M;
        dv = ws + (size_t)2 * NUP * DK; dq = dv + (size_t)NMP * DK;
        nvalid = NM; swz = 0;
    }
    short8 v8 = {0,0,0,0,0,0,0,0}, q8 = {0,0,0,0,0,0,0,0};
    if (row < nvalid) {
        const int cp = swz ? (p ^ (row & 7)) : p;
        const float* s = src + (size_t)row * DK + cp * 8;
        float4 a = *(const float4*)(s);
        float4 b = *(const float4*)(s + 4);
        v8 = (short8){ f2bf(a.x), f2bf(a.y), f2bf(a.z), f2bf(a.w),
                       f2bf(b.x), f2bf(b.y), f2bf(b.z), f2bf(b.w) };
        q8 = (short8){ f2bf(a.x*a.x), f2bf(a.y*a.y), f2bf(a.z*a.z), f2bf(a.w*a.w),
                       f2bf(b.x*b.x), f2bf(b.y*b.y), f2bf(b.z*b.z), f2bf(b.w*b.w) };
    }
    *(short8*)(dv + (size_t)row * DK + p * 8) = v8;
    *(short8*)(dq + (size_t)row * DK + p * 8) = q8;
}

// ---------------- Phase 2: pipelined fused double-GEMM ----------------------
// Block: BN=128 movies (wave owns 32, B frags in regs for whole block) x
// TUSR x 64 users (looped; A staged in double-buffered LDS via global_load_lds).
// Per-iter: issue A-prefetch -> ds_read A -> MFMA (transposed) -> f32x4 NT
// stores -> s_waitcnt vmcnt(8) (loads retired, stores stay in flight) ->
// raw s_barrier. Stores of iter t drain under compute of t+1.
__global__ __launch_bounds__(256, 2)
void fm_gemm(const short* __restrict__ ws, float* __restrict__ out,
             int NM, int NMP, int NUP) {
    __shared__ short sA [2][BM * DK];   // 2 x 8 KB values
    __shared__ short sA2[2][BM * DK];   // 2 x 8 KB squares  -> 32 KB total

    const int t = threadIdx.x;
    const int lane = t & 63;
    const int w = t >> 6;            // wave 0..3 -> movie quadrant
    const int lr = lane & 15;
    const int lk = lane >> 4;

    const int nb = blockIdx.y * BN + w * 32;   // wave's movie base

    const short* gU  = ws;
    const short* gU2 = ws + (size_t)NUP * DK;
    const short* gM  = ws + (size_t)2 * NUP * DK;
    const short* gM2 = gM + (size_t)NMP * DK;

    // B fragments (movies) once per block: [n][ks]
    short8 bv[2][2], bq[2][2];
#pragma unroll
    for (int n = 0; n < 2; ++n)
#pragma unroll
        for (int ks = 0; ks < 2; ++ks) {
            const size_t a = (size_t)(nb + n * 16 + lr) * DK + (ks * 4 + lk) * 8;
            bv[n][ks] = *(const short8*)(gM  + a);
            bq[n][ks] = *(const short8*)(gM2 + a);
        }

    const int ub0 = blockIdx.x * (BM * TUSR);
    const int lo = lane * 8;                    // lane's 16B within a 1KB chunk

    // ---- prologue: stage tile 0 into buffer 0 ----
    {
        const short* srcA  = gU  + (size_t)ub0 * DK;
        const short* srcA2 = gU2 + (size_t)ub0 * DK;
#pragma unroll
        for (int i = 0; i < 2; ++i) {           // 8 KB = 8 x 1KB chunks / 4 waves
            const int ch = w * 2 + i;
            gl_lds16(srcA  + ch * 512 + lo, &sA [0][ch * 512]);
            gl_lds16(srcA2 + ch * 512 + lo, &sA2[0][ch * 512]);
        }
    }
    asm volatile("s_waitcnt vmcnt(0)" ::: "memory");
    __builtin_amdgcn_s_barrier();

#pragma unroll 1
    for (int tt = 0; tt < TUSR; ++tt) {
        const int cur = tt & 1;
        // issue prefetch of next tile early (async, stays in flight)
        if (tt + 1 < TUSR) {
            const int nxt = (tt + 1) & 1;
            const short* srcA  = gU  + (size_t)(ub0 + (tt + 1) * BM) * DK;
            const short* srcA2 = gU2 + (size_t)(ub0 + (tt + 1) * BM) * DK;
#pragma unroll
            for (int i = 0; i < 2; ++i) {
                const int ch = w * 2 + i;
                gl_lds16(srcA  + ch * 512 + lo, &sA [nxt][ch * 512]);
                gl_lds16(srcA2 + ch * 512 + lo, &sA2[nxt][ch * 512]);
            }
        }

        // ds_read A fragments (swizzled): [m][ks]
        short8 av[4][2], aq[4][2];
#pragma unroll
        for (int m = 0; m < 4; ++m)
#pragma unroll
            for (int ks = 0; ks < 2; ++ks) {
                const int row = m * 16 + lr;
                const int c = ks * 4 + lk;
                const int idx = row * DK + ((c ^ (row & 7)) << 3);
                av[m][ks] = *(const short8*)&sA [cur][idx];
                aq[m][ks] = *(const short8*)&sA2[cur][idx];
            }

        f32x4 s[4][2], q[4][2];
#pragma unroll
        for (int m = 0; m < 4; ++m)
#pragma unroll
            for (int n = 0; n < 2; ++n) {
                s[m][n] = (f32x4){0.f, 0.f, 0.f, 0.f};
                q[m][n] = (f32x4){0.f, 0.f, 0.f, 0.f};
            }

#pragma unroll
        for (int m = 0; m < 4; ++m)
#pragma unroll
            for (int n = 0; n < 2; ++n)
#pragma unroll
                for (int ks = 0; ks < 2; ++ks) {
                    // transposed: D[movie][user] -> lane holds 4 consecutive cols
                    s[m][n] = __builtin_amdgcn_mfma_f32_16x16x32_bf16(bv[n][ks], av[m][ks], s[m][n], 0, 0, 0);
                    q[m][n] = __builtin_amdgcn_mfma_f32_16x16x32_bf16(bq[n][ks], aq[m][ks], q[m][n], 0, 0, 0);
                }

        // epilogue: lane -> user row ub+m*16+lr, movie cols nb+n*16+lk*4+{0..3}
        const int ub = ub0 + tt * BM;
#pragma unroll
        for (int m = 0; m < 4; ++m) {
            float* rowp = out + (size_t)(ub + m * 16 + lr) * NM;
#pragma unroll
            for (int n = 0; n < 2; ++n) {
                const int col = nb + n * 16 + lk * 4;
                if (col < NM) {
                    f32x4 sv = s[m][n], qv = q[m][n];
                    f32x4 r;
#pragma unroll
                    for (int i = 0; i < 4; ++i)
                        r[i] = 0.5f * (sv[i] * sv[i] - qv[i]);
                    __builtin_nontemporal_store(r, (f32x4*)(rowp + col));
                }
            }
        }

        // loads (4, oldest) must retire; the 8 stores just issued may remain
        // in flight across the barrier. lgkmcnt(0): all ds ops done.
        asm volatile("s_waitcnt vmcnt(8) lgkmcnt(0)" ::: "memory");
        __builtin_amdgcn_s_barrier();
    }
}

// ---------------- Fallback (round-1 kernel) ---------------------------------
__global__ __launch_bounds__(256, 2)
void fm_fallback(const float* __restrict__ U, const float* __restrict__ M,
                 float* __restrict__ out, int NU, int NM) {
    __shared__ short sA [128 * DK];
    __shared__ short sA2[128 * DK];
    __shared__ short sB [128 * DK];
    __shared__ short sB2[128 * DK];

    const int t = threadIdx.x;
    const int lane = t & 63;
    const int w = t >> 6;
    const int wr = w >> 1;
    const int wc = w & 1;
    const int lr = lane & 15;
    const int lk = lane >> 4;

    const int mbase = blockIdx.x * 128;
    const int nbase = blockIdx.y * 128;

    const int r0 = t >> 4;
    const int c4 = t & 15;
    const int chunk = c4 >> 1;
    const int sub = c4 & 1;

    typedef short short4v __attribute__((ext_vector_type(4)));
#pragma unroll
    for (int i = 0; i < 8; ++i) {
        const int r = r0 + i * 16;
        const int sidx = r * DK + ((chunk ^ (r & 7)) << 3) + (sub << 2);
        {
            float4 v = make_float4(0.f, 0.f, 0.f, 0.f);
            const int gr = mbase + r;
            if (gr < NU) v = *(const float4*)(U + (size_t)gr * DK + c4 * 4);
            short4v b  = { f2bf(v.x), f2bf(v.y), f2bf(v.z), f2bf(v.w) };
            short4v b2 = { f2bf(v.x*v.x), f2bf(v.y*v.y), f2bf(v.z*v.z), f2bf(v.w*v.w) };
            *(short4v*)&sA[sidx] = b; *(short4v*)&sA2[sidx] = b2;
        }
        {
            float4 v = make_float4(0.f, 0.f, 0.f, 0.f);
            const int gr = nbase + r;
            if (gr < NM) v = *(const float4*)(M + (size_t)gr * DK + c4 * 4);
            short4v b  = { f2bf(v.x), f2bf(v.y), f2bf(v.z), f2bf(v.w) };
            short4v b2 = { f2bf(v.x*v.x), f2bf(v.y*v.y), f2bf(v.z*v.z), f2bf(v.w*v.w) };
            *(short4v*)&sB[sidx] = b; *(short4v*)&sB2[sidx] = b2;
        }
    }
    __syncthreads();

    f32x4 accS[4][4], accQ[4][4];
#pragma unroll
    for (int m = 0; m < 4; ++m)
#pragma unroll
        for (int n = 0; n < 4; ++n) {
            accS[m][n] = (f32x4){0.f,0.f,0.f,0.f};
            accQ[m][n] = (f32x4){0.f,0.f,0.f,0.f};
        }
#pragma unroll
    for (int ks = 0; ks < 2; ++ks) {
        short8 af[4], a2f[4], bfr[4], b2f[4];
        const int c = ks * 4 + lk;
#pragma unroll
        for (int m = 0; m < 4; ++m) {
            const int row = wr * 64 + m * 16 + lr;
            const int idx = row * DK + ((c ^ (row & 7)) << 3);
            af[m] = *(const short8*)&sA[idx]; a2f[m] = *(const short8*)&sA2[idx];
        }
#pragma unroll
        for (int n = 0; n < 4; ++n) {
            const int row = wc * 64 + n * 16 + lr;
            const int idx = row * DK + ((c ^ (row & 7)) << 3);
            bfr[n] = *(const short8*)&sB[idx]; b2f[n] = *(const short8*)&sB2[idx];
        }
#pragma unroll
        for (int m = 0; m < 4; ++m)
#pragma unroll
            for (int n = 0; n < 4; ++n) {
                accS[m][n] = __builtin_amdgcn_mfma_f32_16x16x32_bf16(af[m],  bfr[n], accS[m][n], 0, 0, 0);
                accQ[m][n] = __builtin_amdgcn_mfma_f32_16x16x32_bf16(a2f[m], b2f[n], accQ[m][n], 0, 0, 0);
            }
    }
#pragma unroll
    for (int m = 0; m < 4; ++m) {
        const int grow0 = mbase + wr * 64 + m * 16 + lk * 4;
#pragma unroll
        for (int n = 0; n < 4; ++n) {
            const int gcol = nbase + wc * 64 + n * 16 + lr;
            if (gcol < NM) {
                f32x4 s = accS[m][n]; f32x4 q = accQ[m][n];
#pragma unroll
                for (int r = 0; r < 4; ++r) {
                    const int grow = grow0 + r;
                    if (grow < NU)
                        out[(size_t)grow * NM + gcol] = 0.5f * (s[r]*s[r] - q[r]);
                }
            }
        }
    }
}

extern "C" void kernel_launch(void* const* d_in, const int* in_sizes, int n_in,
                              void* d_out, int out_size, void* d_ws, size_t ws_size,
                              hipStream_t stream) {
    const float* U = (const float*)d_in[0];
    const float* M = (const float*)d_in[1];
    float* out = (float*)d_out;
    const int NU = in_sizes[0] / DK;   // 1024
    const int NM = in_sizes[1] / DK;   // 50000
    const int NUP = NU;
    const int NMP = ((NM + 127) / 128) * 128;
    const size_t need = (size_t)(NUP + NMP) * DK * 2 * sizeof(short);

    if ((NU % (BM * TUSR) == 0) && (NM % 4 == 0) && ws_size >= need) {
        short* ws = (short*)d_ws;
        const int tasks = (NUP + NMP) * 8;
        fm_convert<<<(tasks + 255) / 256, 256, 0, stream>>>(U, M, ws, NU, NM, NUP, NMP);
        dim3 grid(NU / (BM * TUSR), NMP / BN);
        fm_gemm<<<grid, dim3(256), 0, stream>>>(ws, out, NM, NMP, NUP);
    } else {
        dim3 grid((NU + 127) / 128, (NM + 127) / 128);
        fm_fallback<<<grid, dim3(256), 0, stream>>>(U, M, out, NU, NM);
    }
}

// Round 5
// 68.222 us; speedup vs baseline: 1.2831x; 1.2037x over previous
//
#include <hip/hip_runtime.h>

typedef short short8 __attribute__((ext_vector_type(8)));
typedef float f32x4 __attribute__((ext_vector_type(4)));

#define DK 64
#define BM 64     // users per block
#define BN 128    // movies per tile
#define TMOV 8    // movie tiles looped per block

// f32 -> bf16 round-to-nearest-even
__device__ __forceinline__ short f2bf(float x) {
    unsigned u = __builtin_bit_cast(unsigned, x);
    unsigned r = (u + 0x7fffu + ((u >> 16) & 1u)) >> 16;
    return (short)r;
}

__device__ __forceinline__ void gl_lds16(const void* g, void* l) {
    __builtin_amdgcn_global_load_lds(
        (const __attribute__((address_space(1))) unsigned int*)g,
        (__attribute__((address_space(3))) unsigned int*)l, 16, 0, 0);
}

// ---------------- Phase 1: bf16 convert (value + square), pre-swizzled ------
// ws (shorts): [wsU: NUP*64][wsU2: NUP*64][wsM: NMP*64][wsM2: NMP*64]
// Rows stored with 16B chunk p holding source chunk p^(row&7): a LINEAR
// global_load_lds copy then yields the XOR-swizzled LDS layout (rule #21).
__global__ __launch_bounds__(256)
void fm_convert(const float* __restrict__ U, const float* __restrict__ M,
                short* __restrict__ ws, int NU, int NM, int NUP, int NMP) {
    int id = blockIdx.x * blockDim.x + threadIdx.x;
    int total = (NUP + NMP) * 8;
    if (id >= total) return;
    int rowg = id >> 3;
    int p = id & 7;                 // 16B chunk within the 64-wide row
    const float* src; short *dv, *dq; int row, nvalid;
    if (rowg < NUP) {
        row = rowg; src = U; dv = ws; dq = ws + (size_t)NUP * DK; nvalid = NU;
    } else {
        row = rowg - NUP; src = M;
        dv = ws + (size_t)2 * NUP * DK; dq = dv + (size_t)NMP * DK; nvalid = NM;
    }
    short8 v8 = {0,0,0,0,0,0,0,0}, q8 = {0,0,0,0,0,0,0,0};
    if (row < nvalid) {
        const int cp = p ^ (row & 7);
        const float* s = src + (size_t)row * DK + cp * 8;
        float4 a = *(const float4*)(s);
        float4 b = *(const float4*)(s + 4);
        v8 = (short8){ f2bf(a.x), f2bf(a.y), f2bf(a.z), f2bf(a.w),
                       f2bf(b.x), f2bf(b.y), f2bf(b.z), f2bf(b.w) };
        q8 = (short8){ f2bf(a.x*a.x), f2bf(a.y*a.y), f2bf(a.z*a.z), f2bf(a.w*a.w),
                       f2bf(b.x*b.x), f2bf(b.y*b.y), f2bf(b.z*b.z), f2bf(b.w*b.w) };
    }
    *(short8*)(dv + (size_t)row * DK + p * 8) = v8;
    *(short8*)(dq + (size_t)row * DK + p * 8) = q8;
}

// ---------------- Phase 2: fused double-GEMM, movie-loop per block ----------
// Block: 64 users (A staged in LDS ONCE) x TMOV x 128 movies (B staged per
// iter; every movie tile staged exactly once across the grid). 48 KB LDS ->
// 3 blocks/CU; inter-block wave overlap hides the stage/compute/store phases.
// MFMA computed transposed (mfma(B,A)): lane holds 4 consecutive movie cols
// of one user row -> float4 stores.
__global__ __launch_bounds__(256, 3)
void fm_gemm(const short* __restrict__ ws, float* __restrict__ out,
             int NM, int NMP, int NUP, int NMT) {
    __shared__ short sA [BM * DK];   // 8 KB user values
    __shared__ short sA2[BM * DK];   // 8 KB user squares
    __shared__ short sB [BN * DK];   // 16 KB movie values
    __shared__ short sB2[BN * DK];   // 16 KB movie squares -> 48 KB

    const int t = threadIdx.x;
    const int lane = t & 63;
    const int w = t >> 6;            // wave 0..3 -> movie quadrant within tile
    const int lr = lane & 15;
    const int lk = lane >> 4;

    const short* gU  = ws;
    const short* gU2 = ws + (size_t)NUP * DK;
    const short* gM  = ws + (size_t)2 * NUP * DK;
    const short* gM2 = gM + (size_t)NMP * DK;

    const int ub = blockIdx.x * BM;
    const int g0 = blockIdx.y * TMOV;
    const int gend = (g0 + TMOV < NMT) ? (g0 + TMOV) : NMT;
    const int lo = lane * 8;         // lane's 16B within a 1KB chunk (shorts)

    // ---- stage A once: 8 KB per array = 8 x 1KB chunks / 4 waves ----
    {
        const short* srcA  = gU  + (size_t)ub * DK;
        const short* srcA2 = gU2 + (size_t)ub * DK;
#pragma unroll
        for (int i = 0; i < 2; ++i) {
            const int ch = w * 2 + i;
            gl_lds16(srcA  + ch * 512 + lo, &sA [ch * 512]);
            gl_lds16(srcA2 + ch * 512 + lo, &sA2[ch * 512]);
        }
    }

#pragma unroll 1
    for (int mt = g0; mt < gend; ++mt) {
        if (mt != g0) __syncthreads();   // B reads of prev iter done

        // ---- stage B tile mt: 16 KB per array = 16 chunks / 4 waves ----
        {
            const short* srcB  = gM  + (size_t)mt * BN * DK;
            const short* srcB2 = gM2 + (size_t)mt * BN * DK;
#pragma unroll
            for (int i = 0; i < 4; ++i) {
                const int ch = w * 4 + i;
                gl_lds16(srcB  + ch * 512 + lo, &sB [ch * 512]);
                gl_lds16(srcB2 + ch * 512 + lo, &sB2[ch * 512]);
            }
        }
        __syncthreads();                 // stage complete (A too on iter 0)

        // ---- fragments (swizzled reads) ----
        short8 av[4][2], aq[4][2];       // users: [m][ks]
#pragma unroll
        for (int m = 0; m < 4; ++m)
#pragma unroll
            for (int ks = 0; ks < 2; ++ks) {
                const int row = m * 16 + lr;
                const int c = ks * 4 + lk;
                const int idx = row * DK + ((c ^ (row & 7)) << 3);
                av[m][ks] = *(const short8*)&sA [idx];
                aq[m][ks] = *(const short8*)&sA2[idx];
            }
        short8 bv[2][2], bq[2][2];       // movies: [n][ks], wave quadrant
#pragma unroll
        for (int n = 0; n < 2; ++n)
#pragma unroll
            for (int ks = 0; ks < 2; ++ks) {
                const int row = w * 32 + n * 16 + lr;
                const int c = ks * 4 + lk;
                const int idx = row * DK + ((c ^ (row & 7)) << 3);
                bv[n][ks] = *(const short8*)&sB [idx];
                bq[n][ks] = *(const short8*)&sB2[idx];
            }

        f32x4 s[4][2], q[4][2];
#pragma unroll
        for (int m = 0; m < 4; ++m)
#pragma unroll
            for (int n = 0; n < 2; ++n) {
                s[m][n] = (f32x4){0.f, 0.f, 0.f, 0.f};
                q[m][n] = (f32x4){0.f, 0.f, 0.f, 0.f};
            }

#pragma unroll
        for (int m = 0; m < 4; ++m)
#pragma unroll
            for (int n = 0; n < 2; ++n)
#pragma unroll
                for (int ks = 0; ks < 2; ++ks) {
                    // transposed: D[movie][user]; lane -> user lr, movies lk*4+reg
                    s[m][n] = __builtin_amdgcn_mfma_f32_16x16x32_bf16(bv[n][ks], av[m][ks], s[m][n], 0, 0, 0);
                    q[m][n] = __builtin_amdgcn_mfma_f32_16x16x32_bf16(bq[n][ks], aq[m][ks], q[m][n], 0, 0, 0);
                }

        // ---- epilogue: user row ub+m*16+lr, movie cols mt*128+w*32+n*16+lk*4 ----
        const int nbW = mt * BN + w * 32;
#pragma unroll
        for (int m = 0; m < 4; ++m) {
            float* rowp = out + (size_t)(ub + m * 16 + lr) * NM;
#pragma unroll
            for (int n = 0; n < 2; ++n) {
                const int col = nbW + n * 16 + lk * 4;
                if (col < NM) {
                    f32x4 sv = s[m][n], qv = q[m][n];
                    f32x4 r;
#pragma unroll
                    for (int i = 0; i < 4; ++i)
                        r[i] = 0.5f * (sv[i] * sv[i] - qv[i]);
                    *(f32x4*)(rowp + col) = r;
                }
            }
        }
    }
}

// ---------------- Fallback (round-1 kernel) ---------------------------------
__global__ __launch_bounds__(256, 2)
void fm_fallback(const float* __restrict__ U, const float* __restrict__ M,
                 float* __restrict__ out, int NU, int NM) {
    __shared__ short sA [128 * DK];
    __shared__ short sA2[128 * DK];
    __shared__ short sB [128 * DK];
    __shared__ short sB2[128 * DK];

    const int t = threadIdx.x;
    const int lane = t & 63;
    const int w = t >> 6;
    const int wr = w >> 1;
    const int wc = w & 1;
    const int lr = lane & 15;
    const int lk = lane >> 4;

    const int mbase = blockIdx.x * 128;
    const int nbase = blockIdx.y * 128;

    const int r0 = t >> 4;
    const int c4 = t & 15;
    const int chunk = c4 >> 1;
    const int sub = c4 & 1;

    typedef short short4v __attribute__((ext_vector_type(4)));
#pragma unroll
    for (int i = 0; i < 8; ++i) {
        const int r = r0 + i * 16;
        const int sidx = r * DK + ((chunk ^ (r & 7)) << 3) + (sub << 2);
        {
            float4 v = make_float4(0.f, 0.f, 0.f, 0.f);
            const int gr = mbase + r;
            if (gr < NU) v = *(const float4*)(U + (size_t)gr * DK + c4 * 4);
            short4v b  = { f2bf(v.x), f2bf(v.y), f2bf(v.z), f2bf(v.w) };
            short4v b2 = { f2bf(v.x*v.x), f2bf(v.y*v.y), f2bf(v.z*v.z), f2bf(v.w*v.w) };
            *(short4v*)&sA[sidx] = b; *(short4v*)&sA2[sidx] = b2;
        }
        {
            float4 v = make_float4(0.f, 0.f, 0.f, 0.f);
            const int gr = nbase + r;
            if (gr < NM) v = *(const float4*)(M + (size_t)gr * DK + c4 * 4);
            short4v b  = { f2bf(v.x), f2bf(v.y), f2bf(v.z), f2bf(v.w) };
            short4v b2 = { f2bf(v.x*v.x), f2bf(v.y*v.y), f2bf(v.z*v.z), f2bf(v.w*v.w) };
            *(short4v*)&sB[sidx] = b; *(short4v*)&sB2[sidx] = b2;
        }
    }
    __syncthreads();

    f32x4 accS[4][4], accQ[4][4];
#pragma unroll
    for (int m = 0; m < 4; ++m)
#pragma unroll
        for (int n = 0; n < 4; ++n) {
            accS[m][n] = (f32x4){0.f,0.f,0.f,0.f};
            accQ[m][n] = (f32x4){0.f,0.f,0.f,0.f};
        }
#pragma unroll
    for (int ks = 0; ks < 2; ++ks) {
        short8 af[4], a2f[4], bfr[4], b2f[4];
        const int c = ks * 4 + lk;
#pragma unroll
        for (int m = 0; m < 4; ++m) {
            const int row = wr * 64 + m * 16 + lr;
            const int idx = row * DK + ((c ^ (row & 7)) << 3);
            af[m] = *(const short8*)&sA[idx]; a2f[m] = *(const short8*)&sA2[idx];
        }
#pragma unroll
        for (int n = 0; n < 4; ++n) {
            const int row = wc * 64 + n * 16 + lr;
            const int idx = row * DK + ((c ^ (row & 7)) << 3);
            bfr[n] = *(const short8*)&sB[idx]; b2f[n] = *(const short8*)&sB2[idx];
        }
#pragma unroll
        for (int m = 0; m < 4; ++m)
#pragma unroll
            for (int n = 0; n < 4; ++n) {
                accS[m][n] = __builtin_amdgcn_mfma_f32_16x16x32_bf16(af[m],  bfr[n], accS[m][n], 0, 0, 0);
                accQ[m][n] = __builtin_amdgcn_mfma_f32_16x16x32_bf16(a2f[m], b2f[n], accQ[m][n], 0, 0, 0);
            }
    }
#pragma unroll
    for (int m = 0; m < 4; ++m) {
        const int grow0 = mbase + wr * 64 + m * 16 + lk * 4;
#pragma unroll
        for (int n = 0; n < 4; ++n) {
            const int gcol = nbase + wc * 64 + n * 16 + lr;
            if (gcol < NM) {
                f32x4 s = accS[m][n]; f32x4 q = accQ[m][n];
#pragma unroll
                for (int r = 0; r < 4; ++r) {
                    const int grow = grow0 + r;
                    if (grow < NU)
                        out[(size_t)grow * NM + gcol] = 0.5f * (s[r]*s[r] - q[r]);
                }
            }
        }
    }
}

extern "C" void kernel_launch(void* const* d_in, const int* in_sizes, int n_in,
                              void* d_out, int out_size, void* d_ws, size_t ws_size,
                              hipStream_t stream) {
    const float* U = (const float*)d_in[0];
    const float* M = (const float*)d_in[1];
    float* out = (float*)d_out;
    const int NU = in_sizes[0] / DK;   // 1024
    const int NM = in_sizes[1] / DK;   // 50000
    const int NUP = NU;
    const int NMP = ((NM + BN - 1) / BN) * BN;
    const int NMT = NMP / BN;          // movie tiles (391)
    const size_t need = (size_t)(NUP + NMP) * DK * 2 * sizeof(short);

    if ((NU % BM == 0) && (NM % 4 == 0) && ws_size >= need) {
        short* ws = (short*)d_ws;
        const int tasks = (NUP + NMP) * 8;
        fm_convert<<<(tasks + 255) / 256, 256, 0, stream>>>(U, M, ws, NU, NM, NUP, NMP);
        dim3 grid(NU / BM, (NMT + TMOV - 1) / TMOV);
        fm_gemm<<<grid, dim3(256), 0, stream>>>(ws, out, NM, NMP, NUP, NMT);
    } else {
        dim3 grid((NU + 127) / 128, (NM + 127) / 128);
        fm_fallback<<<grid, dim3(256), 0, stream>>>(U, M, out, NU, NM);
    }
}